// Round 3
// baseline (398.508 us; speedup 1.0000x reference)
//
#include <hip/hip_runtime.h>

// FELDMSTM: fused AutoCorrelationLayer(FourierBlock) + FFTDecompLayer
// B=8 N=2000 L=96 D=32 H=4 E=8 modes={1,4,5} kavg=25, float32 in/out.
//
// Math folding (exact):
//   q-bias drops (sum of cos/sin over full period = 0); k,v projections unused.
//   CS[d][m]   = sum_l x[l,d] * {cos,sin}(2*pi*m*l/96)        (forward basis)
//   X[c][m]    = sum_d Wq[c,d] * CS[d][m]   (Xre = Wq*Cx, Xim = -Wq*Sx)
//   O[h,o][m]  = sum_e X[h*8+e][m] * (W1 + i*W2)[n,h,e,o,m]
//   Z[d][m]    = sum_c Wo[d,c] * O[c][m]
//   new_x[l,d] = (1/48) * sum_m (Zre*cos - Zim*sin) + bo[d]
//   xr = x + new_x;  trend = 25-tap edge-padded mean;  res = xr - trend.
//
// R2 changes: LDS 34.3KB -> 19.8KB (8 blocks/CU, was 4); W matrices read
// straight from global (L1/L2-hot, no staging); C/E phases are direct
// dot-products on 192 threads (barriers 9 -> 7).

#define N_NODES 2000

__global__ __launch_bounds__(256, 8)
void fused_fourier_decomp(const float* __restrict__ x,
                          const float* __restrict__ Wq,
                          const float* __restrict__ Wo,
                          const float* __restrict__ bo,
                          const float* __restrict__ W1,
                          const float* __restrict__ W2,
                          float* __restrict__ out)
{
  // LDS layout (floats), total 5056 floats = 19.75 KB:
  //   basis [0,768)     stride 8: [l][0..2]=cos, [3..5]=sin, [6..7]=0
  //   CS    [768,1056)  stride 9 (conflict-free scatter writes)
  //   X     [1056,1344) stride 9
  //   O     [1344,1632) stride 9
  //   Z     [1632,1920) stride 9
  //   bo_s  [1920,1952)
  //   xT/pp [1952,5056) xT: 32x97 (bank (d+l)%32); pp (1536) aliases xT --
  //                     pp is dead before xT's first write in phase F.
  __shared__ __align__(16) float smem[5056];
  float* const basis = smem;
  float* const CS    = smem + 768;
  float* const Xs    = smem + 1056;
  float* const Os    = smem + 1344;
  float* const Zs    = smem + 1632;
  float* const bos   = smem + 1920;
  float* const xT    = smem + 1952;
  float* const pp    = smem + 1952;

  const int t = threadIdx.x;
  const int bid = blockIdx.x;           // b*N + n
  const int n = bid % N_NODES;
  const size_t base = (size_t)bid * (96 * 32);

  const int d = t & 31;                 // owned channel / column
  const int g = t >> 5;                 // l-chunk 0..7 (12 rows each)
  const int l0 = g * 12;

  // ---- phase A: x slice into registers (coalesced: row = 128B across lanes)
  const float* xp = x + base + (size_t)l0 * 32 + d;
  float xv[12];
#pragma unroll
  for (int i = 0; i < 12; ++i) xv[i] = xp[i * 32];

  if (t < 32) bos[t] = bo[t];

  // ---- cos/sin basis (exact integer angle reduction, precise sincos)
  if (t < 96) {
    const int modes[3] = {1, 4, 5};
#pragma unroll
    for (int m = 0; m < 3; ++m) {
      int r = (modes[m] * t) % 96;
      float ang = (float)r * (6.28318530717958647692f / 96.0f);
      float sv, cv;
      sincosf(ang, &sv, &cv);
      basis[t * 8 + m] = cv;
      basis[t * 8 + 3 + m] = sv;
    }
    basis[t * 8 + 6] = 0.0f;
    basis[t * 8 + 7] = 0.0f;
  }
  __syncthreads();                                          // [1]

  // ---- phase B: partial CS over own 12 rows, then 8-way reduce
  {
    float a0 = 0.f, a1 = 0.f, a2 = 0.f, a3 = 0.f, a4 = 0.f, a5 = 0.f;
#pragma unroll
    for (int i = 0; i < 12; ++i) {
      const int l = l0 + i;
      const float4 b0 = *(const float4*)&basis[l * 8];
      const float2 b1 = *(const float2*)&basis[l * 8 + 4];
      const float v = xv[i];
      a0 = fmaf(v, b0.x, a0);
      a1 = fmaf(v, b0.y, a1);
      a2 = fmaf(v, b0.z, a2);
      a3 = fmaf(v, b0.w, a3);
      a4 = fmaf(v, b1.x, a4);
      a5 = fmaf(v, b1.y, a5);
    }
    pp[g * 192 + 0 * 32 + d] = a0;
    pp[g * 192 + 1 * 32 + d] = a1;
    pp[g * 192 + 2 * 32 + d] = a2;
    pp[g * 192 + 3 * 32 + d] = a3;
    pp[g * 192 + 4 * 32 + d] = a4;
    pp[g * 192 + 5 * 32 + d] = a5;
  }
  __syncthreads();                                          // [2]
  if (t < 192) {
    const int dd = t & 31, j = t >> 5;
    float s = 0.f;
#pragma unroll
    for (int gg = 0; gg < 8; ++gg) s += pp[gg * 192 + j * 32 + dd];
    CS[dd * 9 + j] = s;
  }
  __syncthreads();                                          // [3]

  // ---- phase C: X = Wq * CS (direct 32-dot on 192 threads; Wq from L1)
  if (t < 192) {
    const int c = t & 31, j = t >> 5;
    const float4* wq4 = (const float4*)(Wq + c * 32);
    float s = 0.f;
#pragma unroll
    for (int q = 0; q < 8; ++q) {
      const float4 w = wq4[q];
      const int dd = q * 4;
      s = fmaf(w.x, CS[(dd + 0) * 9 + j], s);
      s = fmaf(w.y, CS[(dd + 1) * 9 + j], s);
      s = fmaf(w.z, CS[(dd + 2) * 9 + j], s);
      s = fmaf(w.w, CS[(dd + 3) * 9 + j], s);
    }
    Xs[c * 9 + j] = (j < 3) ? s : -s;   // Xim = -sum Wq*Sx (rfft sign)
  }
  __syncthreads();                                          // [4]

  // ---- phase D: per-head complex contraction (einsum bnhem,nheom; W from L2/L3)
  if (t < 96) {
    const int h = t / 24;
    const int r = t - h * 24;
    const int o = r / 3;
    const int m = r - o * 3;
    const float* W1p = W1 + n * 768;
    const float* W2p = W2 + n * 768;
    float re = 0.f, im = 0.f;
#pragma unroll
    for (int e = 0; e < 8; ++e) {
      const int c = h * 8 + e;
      const float xre = Xs[c * 9 + m];
      const float xim = Xs[c * 9 + 3 + m];
      const int wi = (c * 8 + o) * 3 + m;
      const float w1 = W1p[wi], w2 = W2p[wi];
      re = fmaf(xre, w1, re);
      re = fmaf(-xim, w2, re);
      im = fmaf(xre, w2, im);
      im = fmaf(xim, w1, im);
    }
    const int cp = h * 8 + o;
    Os[cp * 9 + m] = re;
    Os[cp * 9 + 3 + m] = im;
  }
  __syncthreads();                                          // [5]

  // ---- phase E: Z = Wo * O (direct 32-dot on 192 threads; Wo from L1)
  if (t < 192) {
    const int c = t & 31, j = t >> 5;
    const float4* wo4 = (const float4*)(Wo + c * 32);
    float s = 0.f;
#pragma unroll
    for (int q = 0; q < 8; ++q) {
      const float4 w = wo4[q];
      const int cc = q * 4;
      s = fmaf(w.x, Os[(cc + 0) * 9 + j], s);
      s = fmaf(w.y, Os[(cc + 1) * 9 + j], s);
      s = fmaf(w.z, Os[(cc + 2) * 9 + j], s);
      s = fmaf(w.w, Os[(cc + 3) * 9 + j], s);
    }
    Zs[c * 9 + j] = s;
  }
  __syncthreads();                                          // [6]

  // ---- phase F: irfft synthesis + bias + residual -> xr (regs) and xT (LDS)
  float xr[12];
  {
    const float zre0 = Zs[d * 9 + 0], zre1 = Zs[d * 9 + 1], zre2 = Zs[d * 9 + 2];
    const float zim0 = Zs[d * 9 + 3], zim1 = Zs[d * 9 + 4], zim2 = Zs[d * 9 + 5];
    const float bov = bos[d];
#pragma unroll
    for (int i = 0; i < 12; ++i) {
      const int l = l0 + i;
      const float4 b0 = *(const float4*)&basis[l * 8]; // (c0,c1,c2,s0)
      const float2 b1 = *(const float2*)&basis[l * 8 + 4]; // (s1,s2)
      const float v = zre0 * b0.x + zre1 * b0.y + zre2 * b0.z
                    - zim0 * b0.w - zim1 * b1.x - zim2 * b1.y;
      const float r = fmaf(v, (1.0f / 48.0f), bov) + xv[i];
      xr[i] = r;
      xT[d * 97 + l] = r;
    }
  }
  __syncthreads();                                          // [7]

  // ---- phase G: 25-tap edge-padded moving average (running window) + store
  {
    const float* col = &xT[d * 97];
    float* op = out + base + (size_t)l0 * 32 + d;
    float lowv[12];
    float S = 0.f;
#pragma unroll
    for (int j = 0; j < 12; ++j) {          // below-window taps l0-12..l0-1 (clamped)
      int idx = l0 - 12 + j;
      idx = idx < 0 ? 0 : idx;
      lowv[j] = col[idx];
      S += lowv[j];
    }
#pragma unroll
    for (int i = 0; i < 12; ++i) S += xr[i]; // own rows l0..l0+11
    {
      int idx = l0 + 12;                     // top tap of first window
      idx = idx > 95 ? 95 : idx;
      S += col[idx];
    }
#pragma unroll
    for (int i = 0; i < 12; ++i) {
      const int l = l0 + i;
      op[i * 32] = xr[i] - S * (1.0f / 25.0f);
      // slide window: drop clamp(l-12), add clamp(l+13)
      int hi = l + 13;
      hi = hi > 95 ? 95 : hi;
      S += col[hi] - lowv[i];
    }
  }
}

extern "C" void kernel_launch(void* const* d_in, const int* in_sizes, int n_in,
                              void* d_out, int out_size, void* d_ws, size_t ws_size,
                              hipStream_t stream) {
  (void)n_in; (void)out_size; (void)d_ws; (void)ws_size;
  const float* x  = (const float*)d_in[0];
  const float* Wq = (const float*)d_in[1];
  // d_in[2]=bq (exactly cancelled), d_in[3..6]=Wk,bk,Wv,bv (unused by output)
  const float* Wo = (const float*)d_in[7];
  const float* bo = (const float*)d_in[8];
  const float* W1 = (const float*)d_in[9];
  const float* W2 = (const float*)d_in[10];
  float* out = (float*)d_out;

  const int blocks = in_sizes[0] / (96 * 32);  // B*N tiles of 96x32
  fused_fourier_decomp<<<blocks, 256, 0, stream>>>(x, Wq, Wo, bo, W1, W2, out);
}